// Round 17
// baseline (233.870 us; speedup 1.0000x reference)
//
#include <hip/hip_runtime.h>
#include <hip/hip_bf16.h>

#define S_LEN 2048
#define HID_D 2048
#define NH 16
#define NKV 4
#define HD 128
#define BATCH 2

typedef __hip_bfloat16 bf16;
using f32x4 = __attribute__((ext_vector_type(4))) float;
using s16x8 = __attribute__((ext_vector_type(8))) short;

__device__ __forceinline__ f32x4 mfma_16x16x32(s16x8 a, s16x8 b, f32x4 c) {
  return __builtin_amdgcn_mfma_f32_16x16x32_bf16(a, b, c, 0, 0, 0);
}

__device__ __forceinline__ void gload16(const void* g, void* l) {
  __builtin_amdgcn_global_load_lds(
      (const __attribute__((address_space(1))) void*)g,
      (__attribute__((address_space(3))) void*)l, 16, 0, 0);
}

__device__ __forceinline__ unsigned int pk2bf(float a, float b) {
  __hip_bfloat16 lo = __float2bfloat16(a), hi = __float2bfloat16(b);
  return ((unsigned int)*(unsigned short*)&hi << 16) | *(unsigned short*)&lo;
}

// ---------------- elementwise convert f32 -> bf16 (x4 per thread) ----------------
__global__ __launch_bounds__(256) void convert_bf16_k(const float* __restrict__ in,
                                                      bf16* __restrict__ out) {
  int i = (blockIdx.x * 256 + threadIdx.x) * 4;
  float4 v = *(const float4*)&in[i];
  out[i + 0] = __float2bfloat16(v.x);
  out[i + 1] = __float2bfloat16(v.y);
  out[i + 2] = __float2bfloat16(v.z);
  out[i + 3] = __float2bfloat16(v.w);
}

// ---------------- tiled transpose + convert: in[K][N] f32 -> out[N][K] bf16 -------
__global__ __launch_bounds__(256) void transpose_convert_k(const float* __restrict__ in,
                                                           bf16* __restrict__ out,
                                                           int K, int N) {
  __shared__ float tile[32][33];
  int n0 = blockIdx.x * 32, k0 = blockIdx.y * 32;
  int tx = threadIdx.x, ty = threadIdx.y;
#pragma unroll
  for (int i = ty; i < 32; i += 8) tile[i][tx] = in[(size_t)(k0 + i) * N + n0 + tx];
  __syncthreads();
#pragma unroll
  for (int i = ty; i < 32; i += 8)
    out[(size_t)(n0 + i) * K + k0 + tx] = __float2bfloat16(tile[tx][i]);
}

// ---------------- 256x256 GEMM v2 (R16 verbatim): 64x128 wave tile; bf16 OUT -----
__global__ __launch_bounds__(512) void gemm256_k(const bf16* __restrict__ A,
                                                 const bf16* __restrict__ Bt,
                                                 bf16* __restrict__ C,
                                                 int M, int N, int K) {
  __shared__ bf16 Asm[2][256 * 64];
  __shared__ bf16 Bsm[2][256 * 64];
  const int tid = threadIdx.x;
  const int lane = tid & 63, wid = tid >> 6;
  const int fr = lane & 15, hi = lane >> 4;

  const int bid = blockIdx.y * gridDim.x + blockIdx.x;
  const int nwg = gridDim.x * gridDim.y;  // 192: %8==0, bijective
  const int swz = (bid & 7) * (nwg >> 3) + (bid >> 3);
  const int m0 = (swz % gridDim.x) * 256;
  const int n0 = (swz / gridDim.x) * 256;

  const bf16* Ag = A + (size_t)m0 * K;
  const bf16* Bg = Bt + (size_t)n0 * K;

  auto stageT = [&](const bf16* src, bf16* ldsBase, int k0) {
#pragma unroll
    for (int c = 0; c < 4; ++c) {
      int byte = tid * 16 + c * 8192;
      int row = byte >> 7;
      int col = byte & 127;
      int colSw = col ^ ((row & 7) << 4);
      gload16((const char*)(src + (size_t)row * K + k0) + colSw,
              (char*)ldsBase + byte);
    }
  };

  f32x4 acc[4][8];
#pragma unroll
  for (int m = 0; m < 4; ++m)
#pragma unroll
    for (int n = 0; n < 8; ++n) acc[m][n] = (f32x4){0.f, 0.f, 0.f, 0.f};

  const int r0 = (wid >> 1) * 64;
  const int c0 = (wid & 1) * 128;
  const int NT = K >> 6;

  stageT(Ag, &Asm[0][0], 0);
  stageT(Bg, &Bsm[0][0], 0);
  asm volatile("s_waitcnt vmcnt(0)" ::: "memory");
  __builtin_amdgcn_s_barrier();

  for (int t = 0; t < NT; ++t) {
    const int cur = t & 1;
    const int nxt = cur ^ 1;
    const int kn = (t + 1) << 6;
    const bool more = (t + 1) < NT;
#pragma unroll
    for (int p = 0; p < 2; ++p) {
      s16x8 af[4], bq[8];
#pragma unroll
      for (int m = 0; m < 4; ++m) {
        int r = r0 + m * 16 + fr;
        int cb = (p * 64 + hi * 16) ^ ((r & 7) << 4);
        af[m] = *(const s16x8*)((const char*)&Asm[cur][0] + r * 128 + cb);
      }
#pragma unroll
      for (int n = 0; n < 8; ++n) {
        int bn = c0 + n * 16 + fr;
        int cb = (p * 64 + hi * 16) ^ ((bn & 7) << 4);
        bq[n] = *(const s16x8*)((const char*)&Bsm[cur][0] + bn * 128 + cb);
      }
      if (p == 0) {
        if (more) {
          stageT(Ag, &Asm[nxt][0], kn);
          stageT(Bg, &Bsm[nxt][0], kn);
        }
      } else {
        asm volatile("s_waitcnt vmcnt(0)" ::: "memory");
      }
      __builtin_amdgcn_s_barrier();

      __builtin_amdgcn_s_setprio(1);
#pragma unroll
      for (int m = 0; m < 4; ++m)
#pragma unroll
        for (int n = 0; n < 8; ++n)
          acc[m][n] = mfma_16x16x32(af[m], bq[n], acc[m][n]);
      __builtin_amdgcn_s_setprio(0);
    }
  }

#pragma unroll
  for (int m = 0; m < 4; ++m)
#pragma unroll
    for (int n = 0; n < 8; ++n) {
      const int row = m0 + r0 + m * 16 + hi * 4;
      const int col = n0 + c0 + n * 16 + fr;
#pragma unroll
      for (int r = 0; r < 4; ++r)
        C[(size_t)(row + r) * N + col] = __float2bfloat16(acc[m][n][r]);
    }
}

// ---------------- 128x128 GEMM for Wo (R15 verbatim: proven) ---------------------
__global__ __launch_bounds__(256) void gemm128sq_k(const bf16* __restrict__ A,
                                                   const bf16* __restrict__ Bt,
                                                   float* __restrict__ C,
                                                   int M, int N, int K) {
  __shared__ bf16 Asm[2][128 * 64];
  __shared__ bf16 Bsm[2][128 * 64];
  const int tid = threadIdx.x;
  const int lane = tid & 63, wid = tid >> 6;
  const int fr = lane & 15, hi = lane >> 4;

  const int bid = blockIdx.y * gridDim.x + blockIdx.x;
  const int nwg = gridDim.x * gridDim.y;  // 512: %8==0, bijective
  const int swz = (bid & 7) * (nwg >> 3) + (bid >> 3);
  const int m0 = (swz % gridDim.x) * 128;
  const int n0 = (swz / gridDim.x) * 128;

  const bf16* Ag = A + (size_t)m0 * K;
  const bf16* Bg = Bt + (size_t)n0 * K;

  auto stageT = [&](const bf16* src, bf16* ldsBase, int k0) {
#pragma unroll
    for (int c = 0; c < 4; ++c) {
      int byte = tid * 16 + c * 4096;
      int row = byte >> 7;
      int col = byte & 127;
      int colSw = col ^ ((row & 7) << 4);
      gload16((const char*)(src + (size_t)row * K + k0) + colSw,
              (char*)ldsBase + byte);
    }
  };

  f32x4 acc[4][4];
#pragma unroll
  for (int m = 0; m < 4; ++m)
#pragma unroll
    for (int n = 0; n < 4; ++n) acc[m][n] = (f32x4){0.f, 0.f, 0.f, 0.f};

  const int r0 = (wid >> 1) * 64;
  const int c0 = (wid & 1) * 64;
  const int NT = K >> 6;

  stageT(Ag, &Asm[0][0], 0);
  stageT(Bg, &Bsm[0][0], 0);
  asm volatile("s_waitcnt vmcnt(0)" ::: "memory");
  __builtin_amdgcn_s_barrier();

  for (int t = 0; t < NT; ++t) {
    const int cur = t & 1;
    const int nxt = cur ^ 1;
    const int kn = (t + 1) << 6;
    const bool more = (t + 1) < NT;
#pragma unroll
    for (int p = 0; p < 2; ++p) {
      s16x8 af[4], bq[4];
#pragma unroll
      for (int m = 0; m < 4; ++m) {
        int r = r0 + m * 16 + fr;
        int cb = (p * 64 + hi * 16) ^ ((r & 7) << 4);
        af[m] = *(const s16x8*)((const char*)&Asm[cur][0] + r * 128 + cb);
      }
#pragma unroll
      for (int n = 0; n < 4; ++n) {
        int bn = c0 + n * 16 + fr;
        int cb = (p * 64 + hi * 16) ^ ((bn & 7) << 4);
        bq[n] = *(const s16x8*)((const char*)&Bsm[cur][0] + bn * 128 + cb);
      }
      if (p == 0) {
        if (more) {
          stageT(Ag, &Asm[nxt][0], kn);
          stageT(Bg, &Bsm[nxt][0], kn);
        }
      } else {
        asm volatile("s_waitcnt vmcnt(0)" ::: "memory");
      }
      __builtin_amdgcn_s_barrier();

      __builtin_amdgcn_s_setprio(1);
#pragma unroll
      for (int m = 0; m < 4; ++m)
#pragma unroll
        for (int n = 0; n < 4; ++n)
          acc[m][n] = mfma_16x16x32(af[m], bq[n], acc[m][n]);
      __builtin_amdgcn_s_setprio(0);
    }
  }

#pragma unroll
  for (int m = 0; m < 4; ++m)
#pragma unroll
    for (int n = 0; n < 4; ++n) {
      const int row = m0 + r0 + m * 16 + hi * 4;
      const int col = n0 + c0 + n * 16 + fr;
#pragma unroll
      for (int r = 0; r < 4; ++r)
        C[(size_t)(row + r) * N + col] = acc[m][n][r];
    }
}

// ---------------- RoPE for Q (bf16 in, pre-scaled by (1/sqrt(HD))*log2(e)) -------
__global__ __launch_bounds__(256) void rope_q_k(const bf16* __restrict__ qkv,
                                                const int* __restrict__ pos_ids,
                                                bf16* __restrict__ Q) {
  int idx = blockIdx.x * 256 + threadIdx.x;
  int i = idx & 63;
  int h = (idx >> 6) & 15;
  int s = (idx >> 10) & 2047;
  int b = idx >> 21;
  const float kscale = 0.12751841418861862f;  // (1/sqrt(128)) * log2(e)
  float pos = (float)pos_ids[b * S_LEN + s];
  float freq = exp2f((float)i * -0.31143075889569023f);
  float ang = pos * freq;
  float sn, cs;
  sincosf(ang, &sn, &cs);
  const bf16* src = qkv + (size_t)(b * S_LEN + s) * 3072 + h * HD + 2 * i;
  float e = __bfloat162float(src[0]), o = __bfloat162float(src[1]);
  bf16* dst = Q + ((size_t)(b * NH + h) * S_LEN + s) * HD + 2 * i;
  dst[0] = __float2bfloat16((e * cs - o * sn) * kscale);
  dst[1] = __float2bfloat16((e * sn + o * cs) * kscale);
}

// ---------------- RoPE for K (bf16 in) -------------------------------------------
__global__ __launch_bounds__(256) void rope_k_k(const bf16* __restrict__ qkv,
                                                const int* __restrict__ pos_ids,
                                                bf16* __restrict__ Kd) {
  int idx = blockIdx.x * 256 + threadIdx.x;
  int i = idx & 63;
  int kvh = (idx >> 6) & 3;
  int s = (idx >> 8) & 2047;
  int b = idx >> 19;
  float pos = (float)pos_ids[b * S_LEN + s];
  float freq = exp2f((float)i * -0.31143075889569023f);
  float ang = pos * freq;
  float sn, cs;
  sincosf(ang, &sn, &cs);
  const bf16* src = qkv + (size_t)(b * S_LEN + s) * 3072 + 2048 + kvh * HD + 2 * i;
  float e = __bfloat162float(src[0]), o = __bfloat162float(src[1]);
  bf16* dst = Kd + ((size_t)(b * NKV + kvh) * S_LEN + s) * HD + 2 * i;
  dst[0] = __float2bfloat16(e * cs - o * sn);
  dst[1] = __float2bfloat16(e * sn + o * cs);
}

// ---------------- V transpose via LDS tile (bf16 in, coalesced both sides) -------
__global__ __launch_bounds__(256) void v_trans_k(const bf16* __restrict__ qkv,
                                                 bf16* __restrict__ Vt) {
  __shared__ unsigned short tile[32][33];
  const int tx = threadIdx.x, ty = threadIdx.y;
  const int s0 = blockIdx.x * 32;
  const int d0 = blockIdx.y * 32;
  const int b = blockIdx.z >> 2, kvh = blockIdx.z & 3;
  const unsigned short* src = (const unsigned short*)qkv + 2560 + kvh * HD;
#pragma unroll
  for (int i = ty; i < 32; i += 8)
    tile[i][tx] = src[(size_t)(b * S_LEN + s0 + i) * 3072 + d0 + tx];
  __syncthreads();
  unsigned short* dst = (unsigned short*)Vt + (size_t)(b * NKV + kvh) * HD * S_LEN;
#pragma unroll
  for (int i = ty; i < 32; i += 8)
    dst[(size_t)(d0 + i) * S_LEN + s0 + tx] = tile[tx][i];
}

// ---------------- causal flash attention v12 -------------------------------------
// REUSE-2 + KVBLK=32 + 8-wave dual-tile blocks (uniform work per block).
// R11 diagnosis: attn is LDS-read-throughput-bound (34 b128 reads per 32 MFMAs =
// ~83 B/cy/CU = m134 ceiling). Fix: wave owns 32 q-rows so each K/V fragment
// read feeds 2 MFMAs (18 reads / 32 MFMAs). Occupancy+balance (R12/R13 traps):
// block = 8 waves = TWO 128-row tiles (waves 0-3 tile pi, 4-7 tile 15-pi)
// sharing one staged K/V stream -> every block does exactly 260 wave-steps;
// grid 256 = 1 block/CU, 8 waves = 2/SIMD; LDS-bound => self-balancing.
// Conflict-floor layouts, no XOR: K in 1040B-padded 1KB chunks (linear gload
// dest, LINEAR coalesced global src); V reg-staged (T14) to 80B-stride rows;
// P 80B-stride rows. All wave accesses at the 8-cy/KB floor.
__global__ __launch_bounds__(512) void attn_k(const bf16* __restrict__ Q,
                                              const bf16* __restrict__ K,
                                              const bf16* __restrict__ Vt,
                                              bf16* __restrict__ Aout) {
  __shared__ __align__(16) char KsB[2][8320];    // 8 chunks x (4 rows x 256B + 16B pad)
  __shared__ __align__(16) char VsB[2][10240];   // 128 rows x 80B (64B data + pad)
  __shared__ __align__(16) char PsB[8][2560];    // per wave: 32 rows x 80B

  const int tid = threadIdx.x;
  const int lane = tid & 63, wid = tid >> 6;
  const int fr = lane & 15, hi = lane >> 4;
  const int pi = blockIdx.x, h = blockIdx.y, b = blockIdx.z;
  const int kvh = h >> 2;
  const bf16* Qh = Q + (size_t)(b * NH + h) * S_LEN * HD;
  const bf16* Kh = K + (size_t)(b * NKV + kvh) * S_LEN * HD;
  const bf16* Vh = Vt + (size_t)(b * NKV + kvh) * HD * S_LEN;

  const int qb = (wid < 4) ? pi : (15 - pi);
  const int q0w = qb * 128 + (wid & 3) * 32;   // wave's 32 rows
  const int nsteps = 4 * (15 - pi) + 4;        // covers the longer tile

  s16x8 qf[2][4];
#pragma unroll
  for (int u = 0; u < 2; ++u)
#pragma unroll
    for (int ks = 0; ks < 4; ++ks)
      qf[u][ks] = *(const s16x8*)&Qh[(size_t)(q0w + u * 16 + fr) * HD + ks * 32 + hi * 8];

  f32x4 o[2][8];
#pragma unroll
  for (int u = 0; u < 2; ++u)
#pragma unroll
    for (int ds = 0; ds < 8; ++ds) o[u][ds] = (f32x4){0.f, 0.f, 0.f, 0.f};
  float lacc[2][4];
#pragma unroll
  for (int u = 0; u < 2; ++u)
#pragma unroll
    for (int r = 0; r < 4; ++r) lacc[u][r] = 0.f;

  // K stage: wave wid stages chunk wid (rows 4*wid..4*wid+3), linear 1KB
  auto stageK = [&](int bufi, int kv0) {
    gload16((const char*)Kh + ((size_t)(kv0 + wid * 4)) * 256 + lane * 16,
            &KsB[bufi][0] + wid * 1040);
  };
  // V reg stage: thread covers 16B of row d
  const int vd = tid >> 2;
  const int vko = (tid & 3) * 8;
  auto vload = [&](int kv0) {
    return *(const s16x8*)&Vh[(size_t)vd * S_LEN + kv0 + vko];
  };

  stageK(0, 0);
  {
    s16x8 v0 = vload(0);
    *(s16x8*)(&VsB[0][0] + vd * 80 + (tid & 3) * 16) = v0;
  }
  __syncthreads();

  int buf = 0;
  for (int s = 0; s < nsteps; ++s) {
    const int kv0 = s * 32;
    const bool more = (s + 1) < nsteps;
    s16x8 vnext = {};
    if (more) {
      stageK(buf ^ 1, kv0 + 32);
      vnext = vload(kv0 + 32);
    }

    if (kv0 <= q0w) {   // wave has unmasked rows this step
      const bool diag = (kv0 == q0w);
      // ---- QK^T: 8 kf reads, 16 MFMAs (each kf feeds both q-frags) ----
      f32x4 sg[2][2];
#pragma unroll
      for (int u = 0; u < 2; ++u)
#pragma unroll
        for (int kv = 0; kv < 2; ++kv) sg[u][kv] = (f32x4){0.f, 0.f, 0.f, 0.f};
#pragma unroll
      for (int kv = 0; kv < 2; ++kv) {
        const int row = 2 * fr + kv;   // sg[kv] col fr <-> K row 2*fr+kv
        const char* kbase = &KsB[buf][0] + (row >> 2) * 1040 + (row & 3) * 256;
#pragma unroll
        for (int ks = 0; ks < 4; ++ks) {
          s16x8 kf = *(const s16x8*)(kbase + ks * 64 + hi * 16);
          sg[0][kv] = mfma_16x16x32(qf[0][ks], kf, sg[0][kv]);
          sg[1][kv] = mfma_16x16x32(qf[1][ks], kf, sg[1][kv]);
        }
      }

      // ---- fixed-ref softmax + packed b32 P store (80B-stride rows) ----
#pragma unroll
      for (int u = 0; u < 2; ++u)
#pragma unroll
        for (int r = 0; r < 4; ++r) {
          float p0 = __builtin_exp2f(sg[u][0][r]);
          float p1 = __builtin_exp2f(sg[u][1][r]);
          if (diag) {   // k-rel = 2*fr+kv, row-rel = u*16+hi*4+r
            const int qrow = u * 16 + hi * 4 + r;
            p0 = (2 * fr <= qrow) ? p0 : 0.f;
            p1 = (2 * fr + 1 <= qrow) ? p1 : 0.f;
          }
          lacc[u][r] += p0 + p1;
          const int prow = u * 16 + hi * 4 + r;
          *(unsigned int*)(&PsB[wid][0] + prow * 80 + fr * 4) = pk2bf(p0, p1);
        }
      __builtin_amdgcn_wave_barrier();

      s16x8 pf[2];
#pragma unroll
      for (int u = 0; u < 2; ++u)
        pf[u] = *(const s16x8*)(&PsB[wid][0] + (u * 16 + fr) * 80 + hi * 16);
      __builtin_amdgcn_wave_barrier();

      // ---- PV: 8 vf reads, 16 MFMAs (each vf feeds both q-frags) ----
#pragma unroll
      for (int ds = 0; ds < 8; ++ds) {
        s16x8 vf = *(const s16x8*)(&VsB[buf][0] + (ds * 16 + fr) * 80 + hi * 16);
        o[0][ds] = mfma_16x16x32(pf[0], vf, o[0][ds]);
        o[1][ds] = mfma_16x16x32(pf[1], vf, o[1][ds]);
      }
    }

    if (more)
      *(s16x8*)(&VsB[buf ^ 1][0] + vd * 80 + (tid & 3) * 16) = vnext;
    __syncthreads();   // drains K gloads + makes V writes visible
    buf ^= 1;
  }

  // ---- epilogue: reduce l across the 16-lane group, normalize, store ----
#pragma unroll
  for (int u = 0; u < 2; ++u)
#pragma unroll
    for (int r = 0; r < 4; ++r) {
      float l = lacc[u][r];
      l += __shfl_xor(l, 1, 16);
      l += __shfl_xor(l, 2, 16);
      l += __shfl_xor(l, 4, 16);
      l += __shfl_xor(l, 8, 16);
      float inv = 1.0f / l;
      const int srow = q0w + u * 16 + hi * 4 + r;
      bf16* orow = Aout + ((size_t)b * S_LEN + srow) * HID_D + h * HD;
#pragma unroll
      for (int ds = 0; ds < 8; ++ds)
        orow[ds * 16 + fr] = __float2bfloat16(o[u][ds][r] * inv);
    }
}

extern "C" void kernel_launch(void* const* d_in, const int* in_sizes, int n_in,
                              void* d_out, int out_size, void* d_ws, size_t ws_size,
                              hipStream_t stream) {
  const float* x = (const float*)d_in[0];
  const int* pos = (const int*)d_in[1];
  // d_in[2] attention_mask: known causal, applied analytically
  const float* Wq = (const float*)d_in[3];
  const float* Wk = (const float*)d_in[4];
  const float* Wv = (const float*)d_in[5];
  const float* Wo = (const float*)d_in[6];
  float* out = (float*)d_out;

  char* ws = (char*)d_ws;
  size_t off = 0;
  auto alloc = [&](size_t bytes) {
    char* p = ws + off;
    off += (bytes + 255) & ~(size_t)255;
    return p;
  };
  bf16* xb = (bf16*)alloc((size_t)4096 * 2048 * 2);
  bf16* WqkvT = (bf16*)alloc((size_t)3072 * 2048 * 2);
  bf16* WoT = (bf16*)alloc((size_t)2048 * 2048 * 2);
  bf16* qkv = (bf16*)alloc((size_t)4096 * 3072 * 2);   // bf16 intermediate
  bf16* Qb = (bf16*)alloc((size_t)BATCH * NH * S_LEN * HD * 2);
  bf16* Kb = (bf16*)alloc((size_t)BATCH * NKV * S_LEN * HD * 2);
  bf16* Vtb = (bf16*)alloc((size_t)BATCH * NKV * HD * S_LEN * 2);
  bf16* aout = (bf16*)qkv;  // alias: qkv dead after rope/v_trans

  convert_bf16_k<<<8192, 256, 0, stream>>>(x, xb);
  dim3 tb(32, 8);
  transpose_convert_k<<<dim3(64, 64), tb, 0, stream>>>(Wq, WqkvT, 2048, 2048);
  transpose_convert_k<<<dim3(16, 64), tb, 0, stream>>>(Wk, WqkvT + (size_t)2048 * 2048, 2048, 512);
  transpose_convert_k<<<dim3(16, 64), tb, 0, stream>>>(Wv, WqkvT + (size_t)2560 * 2048, 2048, 512);
  transpose_convert_k<<<dim3(64, 64), tb, 0, stream>>>(Wo, WoT, 2048, 2048);

  gemm256_k<<<dim3(16, 12), 512, 0, stream>>>(xb, WqkvT, qkv, 4096, 3072, 2048);

  rope_q_k<<<16384, 256, 0, stream>>>(qkv, pos, Qb);
  rope_k_k<<<4096, 256, 0, stream>>>(qkv, pos, Kb);
  v_trans_k<<<dim3(64, 4, 8), tb, 0, stream>>>(qkv, Vtb);

  attn_k<<<dim3(8, NH, BATCH), 512, 0, stream>>>(Qb, Kb, Vtb, aout);

  gemm128sq_k<<<dim3(32, 16), 256, 0, stream>>>(aout, WoT, out, 4096, 2048, 2048);
}